// Round 11
// baseline (195.756 us; speedup 1.0000x reference)
//
#include <hip/hip_runtime.h>
#include <math.h>

#define BB 4096
#define NN 8192
#define EPSF 1e-8f

typedef float f32x4 __attribute__((ext_vector_type(4)));
typedef unsigned short u16x4 __attribute__((ext_vector_type(4)));

// ws float layout (MODE 1):
// [0, 8192)      : per-block scalar partials: blk*4 + {conc,conf,rank,nok}
// [8192, 16384)  : final colsum (atomic target, zeroed by initcol_k)
// [16384, ...)   : bf16 colsum partials [2048][8192] (33.55 MB)
// MODE 0 fallback: SCAL scalars + CS colsum, all atomic.
#define CS   8192
#define PPF  16384
#define SCAL 4096

__device__ __forceinline__ unsigned short f2bf(float f) {
    union { float f; unsigned u; } v; v.f = f;
    unsigned u = v.u + 0x7FFF + ((v.u >> 16) & 1);   // RNE
    return (unsigned short)(u >> 16);
}

__global__ void initcol_k(float* __restrict__ ws) {
    int i = blockIdx.x * blockDim.x + threadIdx.x;
    if (i < NN) ws[CS + i] = 0.f;
}

__global__ void init_ws(float* __restrict__ ws) {
    int i = blockIdx.x * blockDim.x + threadIdx.x;
    if (i < 12288) ws[SCAL + i] = 0.f;
}

// Fused, no LDS staging: block owns 2 rows. Phase 1 reads w CACHED
// (allocates L2/L3) for rowsums; phase 2 re-reads w cached (L2/L3 hit,
// NT streams can't evict it) + NT-streams the other 4 arrays.
// No LDS tile -> 4 blocks/CU (launch_bounds(512,8)).
template<int MODE>   // 0: atomic colsum+scalars, 1: bf16 partials
__global__ __launch_bounds__(512, 8) void main_k(
    const float* __restrict__ pr, const float* __restrict__ w,
    const float* __restrict__ cf, const float* __restrict__ ar,
    const float* __restrict__ mk, const float* __restrict__ sc,
    float* ws)
{
    __shared__ float rpark[8][2];     // [wave][row] rowsum partials
    __shared__ float park[2][8][8];   // [row][wave][7 vals]

    const int t = threadIdx.x;
    const int wave = t >> 6, lane = t & 63;
    const int rowBase = blockIdx.x * 2;

    const size_t rbase = (size_t)rowBase * (NN / 4);
    const f32x4* w4 = (const f32x4*)w;
    const f32x4* m4 = (const f32x4*)mk;
    const f32x4* c4 = (const f32x4*)cf;
    const f32x4* a4 = (const f32x4*)ar;
    const f32x4* s4 = (const f32x4*)sc;

    // ---- phase 1: rowsums from cached w reads (warms L2/L3) ----
    float rs0, rs1;
    {
        float rsv[2];
#pragma unroll
        for (int rr = 0; rr < 2; ++rr) {
            float acc = 0.f;
#pragma unroll
            for (int j = 0; j < 4; ++j) {
                const f32x4 v = w4[rbase + rr * 2048 + j * 512 + t];
                acc += (v.x + v.y) + (v.z + v.w);
            }
            rsv[rr] = acc;
        }
        rs0 = rsv[0]; rs1 = rsv[1];
    }
#pragma unroll
    for (int off = 32; off; off >>= 1) {
        rs0 += __shfl_xor(rs0, off);
        rs1 += __shfl_xor(rs1, off);
    }
    if (lane == 0) { rpark[wave][0] = rs0; rpark[wave][1] = rs1; }
    __syncthreads();   // barrier 1: rowsum partials visible

    float inv[2];
#pragma unroll
    for (int r = 0; r < 2; ++r) {
        float acc = 0.f;
#pragma unroll
        for (int k = 0; k < 8; ++k) acc += rpark[k][r];
        inv[r] = 1.f / (acc + EPSF);
    }

    float csum[16];
#pragma unroll
    for (int j = 0; j < 16; ++j) csum[j] = 0.f;

    // ---- phase 2: w cached (L2/L3 hit), other 4 arrays NT ----
    // no max-subtraction needed: 20*ar in +-3, sc in +-6 -> exp safe in fp32
#define PROC(WK, MKV, CK, RK, SK, IDX) {                          \
        const float wk = (WK), mval = (MKV);                      \
        conc = fmaf(wk, __logf(wk + EPSF), conc);                 \
        const float wmk = wk * mval;                              \
        tw += wmk; scf = fmaf(wmk, (CK), scf);                    \
        nv += mval;                                               \
        const float er = __expf((RK) * 20.f) * mval;              \
        Zr += er; A = fmaf(er, (SK), A);                          \
        Zs = fmaf(__expf((SK)), mval, Zs);                        \
        csum[IDX] = fmaf(wmk, invr, csum[IDX]); }

#pragma unroll
    for (int rr = 0; rr < 2; ++rr) {
        const size_t base = rbase + (size_t)rr * (NN / 4) + t;
        const float invr = inv[rr];
        float conc = 0.f, scf = 0.f, tw = 0.f, nv = 0.f;
        float Zr = 0.f, A = 0.f, Zs = 0.f;
#pragma unroll
        for (int j = 0; j < 4; ++j) {
            const f32x4 wv = w4[base + j * 512];
            const f32x4 mv = __builtin_nontemporal_load(m4 + base + j * 512);
            const f32x4 cv = __builtin_nontemporal_load(c4 + base + j * 512);
            const f32x4 rv = __builtin_nontemporal_load(a4 + base + j * 512);
            const f32x4 sv = __builtin_nontemporal_load(s4 + base + j * 512);
            PROC(wv.x, mv.x, cv.x, rv.x, sv.x, j * 4 + 0)
            PROC(wv.y, mv.y, cv.y, rv.y, sv.y, j * 4 + 1)
            PROC(wv.z, mv.z, cv.z, rv.z, sv.z, j * 4 + 2)
            PROC(wv.w, mv.w, cv.w, rv.w, sv.w, j * 4 + 3)
        }
#pragma unroll
        for (int off = 32; off; off >>= 1) {
            conc += __shfl_xor(conc, off);
            scf  += __shfl_xor(scf, off);
            tw   += __shfl_xor(tw, off);
            nv   += __shfl_xor(nv, off);
            Zr   += __shfl_xor(Zr, off);
            A    += __shfl_xor(A, off);
            Zs   += __shfl_xor(Zs, off);
        }
        if (lane == 0) {
            float* p = park[rr][wave];
            p[0] = conc; p[1] = scf; p[2] = tw; p[3] = nv;
            p[4] = Zr;   p[5] = A;   p[6] = Zs;
        }
    }
#undef PROC

    // ---- colsum flush ----
    if (MODE == 1) {
        unsigned short* bfrow = (unsigned short*)(ws + PPF) + (size_t)blockIdx.x * NN;
#pragma unroll
        for (int j = 0; j < 4; ++j) {
            u16x4 v;
            v.x = f2bf(csum[j * 4 + 0]); v.y = f2bf(csum[j * 4 + 1]);
            v.z = f2bf(csum[j * 4 + 2]); v.w = f2bf(csum[j * 4 + 3]);
            __builtin_nontemporal_store(v, (u16x4*)bfrow + t + j * 512);
        }
    } else {
#pragma unroll
        for (int j = 0; j < 4; ++j) {
            const int f4 = t + j * 512;
            atomicAdd(&ws[CS + 4 * f4 + 0], csum[j * 4 + 0]);
            atomicAdd(&ws[CS + 4 * f4 + 1], csum[j * 4 + 1]);
            atomicAdd(&ws[CS + 4 * f4 + 2], csum[j * 4 + 2]);
            atomicAdd(&ws[CS + 4 * f4 + 3], csum[j * 4 + 3]);
        }
    }

    __syncthreads();   // barrier 2: park slots visible

    if (t < 64) {      // wave 0: lanes 0..1 finalize the block's 2 rows
        float c0 = 0.f, c1 = 0.f, c2 = 0.f, c3 = 0.f;
        if (lane < 2) {
            float CO = 0, SC = 0, TW = 0, NV = 0, ZR = 0, AA = 0, ZS = 0;
#pragma unroll
            for (int k = 0; k < 8; ++k) {
                const float* p = park[lane][k];
                CO += p[0]; SC += p[1]; TW += p[2]; NV += p[3];
                ZR += p[4]; AA += p[5]; ZS += p[6];
            }
            c0 = CO;
            const float psc = SC / (TW + EPSF);
            const float ct = 1.f / (1.f + __expf(-50.f * pr[rowBase + lane]));
            const float d = psc - ct;
            c1 = d * d;
            if (NV >= 2.f) {
                c2 = (__logf(ZS) - AA / ZR) / NV;   // per-sample ListNet loss
                c3 = 1.f;
            }
        }
        c0 += __shfl_xor(c0, 1);
        c1 += __shfl_xor(c1, 1);
        c2 += __shfl_xor(c2, 1);
        c3 += __shfl_xor(c3, 1);
        if (lane == 0) {
            if (MODE == 1) {
                float* dst = ws + (size_t)blockIdx.x * 4;
                dst[0] = c0; dst[1] = c1; dst[2] = c2; dst[3] = c3;
            } else {
                atomicAdd(&ws[SCAL + 0], c0);
                atomicAdd(&ws[SCAL + 1], c1);
                atomicAdd(&ws[SCAL + 2], c2);
                atomicAdd(&ws[SCAL + 3], c3);
            }
        }
    }
}

// bf16 partial reduce: grid (16,64) x 128 thr; thread sums 32 partial rows
// for its 4 cols, one atomicAdd per col into the final colsum.
__global__ __launch_bounds__(128) void colreduce_k(const unsigned short* __restrict__ src,
                                                   float* __restrict__ ws) {
    const int col4 = blockIdx.x * 128 + threadIdx.x;   // 0..2047 (x4 cols)
    const int k0 = blockIdx.y * 32;
    const u16x4* s4 = (const u16x4*)src;
    float a0 = 0.f, a1 = 0.f, a2 = 0.f, a3 = 0.f;
    for (int k = 0; k < 32; ++k) {
        const u16x4 v = s4[(size_t)(k0 + k) * (NN / 4) + col4];
        union { unsigned u; float f; } b;
        b.u = (unsigned)v.x << 16; a0 += b.f;
        b.u = (unsigned)v.y << 16; a1 += b.f;
        b.u = (unsigned)v.z << 16; a2 += b.f;
        b.u = (unsigned)v.w << 16; a3 += b.f;
    }
    atomicAdd(&ws[CS + col4 * 4 + 0], a0);
    atomicAdd(&ws[CS + col4 * 4 + 1], a1);
    atomicAdd(&ws[CS + col4 * 4 + 2], a2);
    atomicAdd(&ws[CS + col4 * 4 + 3], a3);
}

__device__ __forceinline__ float block_sum_1024(float v) {
    __shared__ float scm[16];
#pragma unroll
    for (int off = 32; off; off >>= 1) v += __shfl_xor(v, off);
    if ((threadIdx.x & 63) == 0) scm[threadIdx.x >> 6] = v;
    __syncthreads();
    if (threadIdx.x == 0) {
        float a = 0.f;
        for (int k = 0; k < 16; ++k) a += scm[k];
        scm[0] = a;
    }
    __syncthreads();
    float r = scm[0];
    __syncthreads();
    return r;
}

template<int MODE>
__global__ __launch_bounds__(1024) void finalize(
    const float* __restrict__ pr, const float* __restrict__ ws,
    float* __restrict__ out)
{
    __shared__ float colLDS[NN];   // 32 KB
    const int t = threadIdx.x;

    float s = 0.f, ssq = 0.f;
    for (int i = t; i < BB; i += 1024) { float v = pr[i]; s += v; ssq = fmaf(v, v, ssq); }

    float p0 = 0.f, p1 = 0.f, p2 = 0.f, p3 = 0.f;
    if (MODE == 1) {
        for (int b = t; b < 2048; b += 1024) {
            p0 += ws[b * 4 + 0]; p1 += ws[b * 4 + 1];
            p2 += ws[b * 4 + 2]; p3 += ws[b * 4 + 3];
        }
    }

    float Tc = 0.f;
    for (int i = t; i < NN; i += 1024) {
        float cs = ws[CS + i];
        colLDS[i] = cs;
        Tc += cs;
    }

    float S  = block_sum_1024(s);
    float SS = block_sum_1024(ssq);
    float T  = block_sum_1024(Tc);
    float C0, C1, C2, C3;
    if (MODE == 1) {
        C0 = block_sum_1024(p0); C1 = block_sum_1024(p1);
        C2 = block_sum_1024(p2); C3 = block_sum_1024(p3);
    } else {
        C0 = ws[SCAL + 0]; C1 = ws[SCAL + 1];
        C2 = ws[SCAL + 2]; C3 = ws[SCAL + 3];
    }

    const float mean = S / (float)BB;
    const float denom = T / (float)BB + EPSF;

    float ent = 0.f;
    for (int i = t; i < NN; i += 1024) {
        float a = colLDS[i] / (float)BB;
        float na = a / denom;
        ent = fmaf(na, __logf(na + EPSF), ent);
    }
    float ENT = block_sum_1024(ent);  // = -batch_entropy = bent_loss

    if (t == 0) {
        float var = (SS - (float)BB * mean * mean) / (float)(BB - 1);
        float sd = sqrtf(fmaxf(var, 0.f));
        float sharpe = -mean / (sd + 0.01f);
        sharpe = fminf(fmaxf(sharpe, -10.f), 10.f);
        float conc_loss = -C0 / (float)BB;
        float conf_loss =  C1 / (float)BB;
        float aux = (C3 > 0.f) ? C2 / fmaxf(C3, 1.f) : 0.f;
        out[0] = 1.0f * (-mean)
               + 0.1f * sharpe
               + 0.01f * conc_loss
               + 0.1f * conf_loss
               + 0.01f * ENT
               + 0.1f * aux;
    }
}

extern "C" void kernel_launch(void* const* d_in, const int* in_sizes, int n_in,
                              void* d_out, int out_size, void* d_ws, size_t ws_size,
                              hipStream_t stream) {
    const float* pr = (const float*)d_in[0];
    const float* w  = (const float*)d_in[1];
    const float* cf = (const float*)d_in[2];
    const float* ar = (const float*)d_in[3];
    const float* mk = (const float*)d_in[4];
    const float* sc = (const float*)d_in[5];
    float* ws = (float*)d_ws;
    float* out = (float*)d_out;

    const size_t bfNeed = (size_t)PPF * 4 + (size_t)2048 * NN * 2;  // ~33.6 MB

    if (ws_size >= bfNeed) {
        initcol_k<<<32, 256, 0, stream>>>(ws);
        main_k<1><<<2048, 512, 0, stream>>>(pr, w, cf, ar, mk, sc, ws);
        colreduce_k<<<dim3(16, 64), 128, 0, stream>>>(
            (const unsigned short*)(ws + PPF), ws);
        finalize<1><<<1, 1024, 0, stream>>>(pr, ws, out);
    } else {
        init_ws<<<48, 256, 0, stream>>>(ws);
        main_k<0><<<2048, 512, 0, stream>>>(pr, w, cf, ar, mk, sc, ws);
        finalize<0><<<1, 1024, 0, stream>>>(pr, ws, out);
    }
}

// Round 12
// 145.632 us; speedup vs baseline: 1.3442x; 1.3442x over previous
//
#include <hip/hip_runtime.h>
#include <math.h>

#define BB 4096
#define NN 8192
#define EPSF 1e-8f

typedef float f32x4 __attribute__((ext_vector_type(4)));
typedef unsigned short u16x4 __attribute__((ext_vector_type(4)));

// ws float layout (MODE 1):
// [0, 8192)      : per-block scalar partials: blk*4 + {conc,conf,rank,nok}
// [8192, 16384)  : final colsum (atomic target, zeroed by main_k block 0)
// [16384, ...)   : bf16 colsum partials [2048][8192] (33.55 MB)
// MODE 0 fallback: SCAL scalars + CS colsum, all atomic.
#define CS   8192
#define PPF  16384
#define SCAL 4096

__device__ __forceinline__ unsigned short f2bf(float f) {
    union { float f; unsigned u; } v; v.f = f;
    unsigned u = v.u + 0x7FFF + ((v.u >> 16) & 1);   // RNE
    return (unsigned short)(u >> 16);
}

__global__ void init_ws(float* __restrict__ ws) {
    int i = blockIdx.x * blockDim.x + threadIdx.x;
    if (i < 12288) ws[SCAL + i] = 0.f;
}

// Fused, LDS-staged, 1024-thread blocks: block owns 2 rows; thread t owns
// f32x4 groups {t, t+1024} of each row. Phase 1 NT-streams w once into the
// 64 KB LDS tile + rowsums; phase 2: w from LDS + 4 NT streams.
// 16 waves/block, 64 KB LDS -> 2 blocks/CU = 32 waves/CU if VGPR<=64.
template<int MODE>   // 0: atomic colsum+scalars, 1: bf16 partials
__global__ __launch_bounds__(1024) void main_k(
    const float* __restrict__ pr, const float* __restrict__ w,
    const float* __restrict__ cf, const float* __restrict__ ar,
    const float* __restrict__ mk, const float* __restrict__ sc,
    float* ws)
{
    extern __shared__ f32x4 wlds[];   // 2 rows * 2048 f32x4 = 64 KB
    __shared__ float rpark[16][2];    // [wave][row] rowsum partials
    __shared__ float park[2][16][8];  // [row][wave][7 vals]

    const int t = threadIdx.x;
    const int wave = t >> 6, lane = t & 63;
    const int rowBase = blockIdx.x * 2;

    // fold initcol: block 0 zeroes the atomic colsum target (consumed only
    // by colreduce_k, which launches after this kernel completes).
    if (MODE == 1 && blockIdx.x == 0) {
#pragma unroll
        for (int j = 0; j < 8; ++j) ws[CS + j * 1024 + t] = 0.f;
    }

    const size_t rbase = (size_t)rowBase * (NN / 4);
    const f32x4* w4 = (const f32x4*)w;
    const f32x4* m4 = (const f32x4*)mk;
    const f32x4* c4 = (const f32x4*)cf;
    const f32x4* a4 = (const f32x4*)ar;
    const f32x4* s4 = (const f32x4*)sc;

    // ---- phase 1: w -> LDS (4 NT loads), rowsums on the fly ----
    float rs0, rs1;
    {
        float rsv[2];
#pragma unroll
        for (int rr = 0; rr < 2; ++rr) {
            float acc = 0.f;
#pragma unroll
            for (int j = 0; j < 2; ++j) {
                const int idx = rr * 2048 + j * 1024 + t;
                const f32x4 v = __builtin_nontemporal_load(w4 + rbase + idx);
                wlds[idx] = v;
                acc += (v.x + v.y) + (v.z + v.w);
            }
            rsv[rr] = acc;
        }
        rs0 = rsv[0]; rs1 = rsv[1];
    }
#pragma unroll
    for (int off = 32; off; off >>= 1) {
        rs0 += __shfl_xor(rs0, off);
        rs1 += __shfl_xor(rs1, off);
    }
    if (lane == 0) { rpark[wave][0] = rs0; rpark[wave][1] = rs1; }
    __syncthreads();   // barrier 1: w tile + rowsum partials visible

    float inv[2];
#pragma unroll
    for (int r = 0; r < 2; ++r) {
        float acc = 0.f;
#pragma unroll
        for (int k = 0; k < 16; ++k) acc += rpark[k][r];
        inv[r] = 1.f / (acc + EPSF);
    }

    float csum[8];
#pragma unroll
    for (int j = 0; j < 8; ++j) csum[j] = 0.f;

    // ---- phase 2: w from LDS, stream the other 4 arrays (NT) ----
    // no max-subtraction needed: 20*ar in +-3, sc in +-6 -> exp safe in fp32
#define PROC(WK, MKV, CK, RK, SK, IDX) {                          \
        const float wk = (WK), mval = (MKV);                      \
        conc = fmaf(wk, __logf(wk + EPSF), conc);                 \
        const float wmk = wk * mval;                              \
        tw += wmk; scf = fmaf(wmk, (CK), scf);                    \
        nv += mval;                                               \
        const float er = __expf((RK) * 20.f) * mval;              \
        Zr += er; A = fmaf(er, (SK), A);                          \
        Zs = fmaf(__expf((SK)), mval, Zs);                        \
        csum[IDX] = fmaf(wmk, invr, csum[IDX]); }

#pragma unroll
    for (int rr = 0; rr < 2; ++rr) {
        const size_t base = rbase + (size_t)rr * (NN / 4) + t;
        const float invr = inv[rr];
        float conc = 0.f, scf = 0.f, tw = 0.f, nv = 0.f;
        float Zr = 0.f, A = 0.f, Zs = 0.f;
#pragma unroll
        for (int j = 0; j < 2; ++j) {
            const f32x4 wv = wlds[rr * 2048 + j * 1024 + t];
            const f32x4 mv = __builtin_nontemporal_load(m4 + base + j * 1024);
            const f32x4 cv = __builtin_nontemporal_load(c4 + base + j * 1024);
            const f32x4 rv = __builtin_nontemporal_load(a4 + base + j * 1024);
            const f32x4 sv = __builtin_nontemporal_load(s4 + base + j * 1024);
            PROC(wv.x, mv.x, cv.x, rv.x, sv.x, j * 4 + 0)
            PROC(wv.y, mv.y, cv.y, rv.y, sv.y, j * 4 + 1)
            PROC(wv.z, mv.z, cv.z, rv.z, sv.z, j * 4 + 2)
            PROC(wv.w, mv.w, cv.w, rv.w, sv.w, j * 4 + 3)
        }
#pragma unroll
        for (int off = 32; off; off >>= 1) {
            conc += __shfl_xor(conc, off);
            scf  += __shfl_xor(scf, off);
            tw   += __shfl_xor(tw, off);
            nv   += __shfl_xor(nv, off);
            Zr   += __shfl_xor(Zr, off);
            A    += __shfl_xor(A, off);
            Zs   += __shfl_xor(Zs, off);
        }
        if (lane == 0) {
            float* p = park[rr][wave];
            p[0] = conc; p[1] = scf; p[2] = tw; p[3] = nv;
            p[4] = Zr;   p[5] = A;   p[6] = Zs;
        }
    }
#undef PROC

    // ---- colsum flush: thread's 8 columns, 2 rows summed ----
    if (MODE == 1) {
        unsigned short* bfrow = (unsigned short*)(ws + PPF) + (size_t)blockIdx.x * NN;
#pragma unroll
        for (int j = 0; j < 2; ++j) {
            u16x4 v;
            v.x = f2bf(csum[j * 4 + 0]); v.y = f2bf(csum[j * 4 + 1]);
            v.z = f2bf(csum[j * 4 + 2]); v.w = f2bf(csum[j * 4 + 3]);
            __builtin_nontemporal_store(v, (u16x4*)bfrow + t + j * 1024);
        }
    } else {
#pragma unroll
        for (int j = 0; j < 2; ++j) {
            const int f4 = t + j * 1024;
            atomicAdd(&ws[CS + 4 * f4 + 0], csum[j * 4 + 0]);
            atomicAdd(&ws[CS + 4 * f4 + 1], csum[j * 4 + 1]);
            atomicAdd(&ws[CS + 4 * f4 + 2], csum[j * 4 + 2]);
            atomicAdd(&ws[CS + 4 * f4 + 3], csum[j * 4 + 3]);
        }
    }

    __syncthreads();   // barrier 2: park slots visible

    if (t < 64) {      // wave 0: lanes 0..1 finalize the block's 2 rows
        float c0 = 0.f, c1 = 0.f, c2 = 0.f, c3 = 0.f;
        if (lane < 2) {
            float CO = 0, SC = 0, TW = 0, NV = 0, ZR = 0, AA = 0, ZS = 0;
#pragma unroll
            for (int k = 0; k < 16; ++k) {
                const float* p = park[lane][k];
                CO += p[0]; SC += p[1]; TW += p[2]; NV += p[3];
                ZR += p[4]; AA += p[5]; ZS += p[6];
            }
            c0 = CO;
            const float psc = SC / (TW + EPSF);
            const float ct = 1.f / (1.f + __expf(-50.f * pr[rowBase + lane]));
            const float d = psc - ct;
            c1 = d * d;
            if (NV >= 2.f) {
                c2 = (__logf(ZS) - AA / ZR) / NV;   // per-sample ListNet loss
                c3 = 1.f;
            }
        }
        c0 += __shfl_xor(c0, 1);
        c1 += __shfl_xor(c1, 1);
        c2 += __shfl_xor(c2, 1);
        c3 += __shfl_xor(c3, 1);
        if (lane == 0) {
            if (MODE == 1) {
                float* dst = ws + (size_t)blockIdx.x * 4;
                dst[0] = c0; dst[1] = c1; dst[2] = c2; dst[3] = c3;
            } else {
                atomicAdd(&ws[SCAL + 0], c0);
                atomicAdd(&ws[SCAL + 1], c1);
                atomicAdd(&ws[SCAL + 2], c2);
                atomicAdd(&ws[SCAL + 3], c3);
            }
        }
    }
}

// bf16 partial reduce: grid (16,64) x 128 thr; thread sums 32 partial rows
// for its 4 cols, one atomicAdd per col into the final colsum.
__global__ __launch_bounds__(128) void colreduce_k(const unsigned short* __restrict__ src,
                                                   float* __restrict__ ws) {
    const int col4 = blockIdx.x * 128 + threadIdx.x;   // 0..2047 (x4 cols)
    const int k0 = blockIdx.y * 32;
    const u16x4* s4 = (const u16x4*)src;
    float a0 = 0.f, a1 = 0.f, a2 = 0.f, a3 = 0.f;
    for (int k = 0; k < 32; ++k) {
        const u16x4 v = s4[(size_t)(k0 + k) * (NN / 4) + col4];
        union { unsigned u; float f; } b;
        b.u = (unsigned)v.x << 16; a0 += b.f;
        b.u = (unsigned)v.y << 16; a1 += b.f;
        b.u = (unsigned)v.z << 16; a2 += b.f;
        b.u = (unsigned)v.w << 16; a3 += b.f;
    }
    atomicAdd(&ws[CS + col4 * 4 + 0], a0);
    atomicAdd(&ws[CS + col4 * 4 + 1], a1);
    atomicAdd(&ws[CS + col4 * 4 + 2], a2);
    atomicAdd(&ws[CS + col4 * 4 + 3], a3);
}

__device__ __forceinline__ float block_sum_1024(float v) {
    __shared__ float scm[16];
#pragma unroll
    for (int off = 32; off; off >>= 1) v += __shfl_xor(v, off);
    if ((threadIdx.x & 63) == 0) scm[threadIdx.x >> 6] = v;
    __syncthreads();
    if (threadIdx.x == 0) {
        float a = 0.f;
        for (int k = 0; k < 16; ++k) a += scm[k];
        scm[0] = a;
    }
    __syncthreads();
    float r = scm[0];
    __syncthreads();
    return r;
}

template<int MODE>
__global__ __launch_bounds__(1024) void finalize(
    const float* __restrict__ pr, const float* __restrict__ ws,
    float* __restrict__ out)
{
    __shared__ float colLDS[NN];   // 32 KB
    const int t = threadIdx.x;

    float s = 0.f, ssq = 0.f;
    for (int i = t; i < BB; i += 1024) { float v = pr[i]; s += v; ssq = fmaf(v, v, ssq); }

    float p0 = 0.f, p1 = 0.f, p2 = 0.f, p3 = 0.f;
    if (MODE == 1) {
        for (int b = t; b < 2048; b += 1024) {
            p0 += ws[b * 4 + 0]; p1 += ws[b * 4 + 1];
            p2 += ws[b * 4 + 2]; p3 += ws[b * 4 + 3];
        }
    }

    float Tc = 0.f;
    for (int i = t; i < NN; i += 1024) {
        float cs = ws[CS + i];
        colLDS[i] = cs;
        Tc += cs;
    }

    float S  = block_sum_1024(s);
    float SS = block_sum_1024(ssq);
    float T  = block_sum_1024(Tc);
    float C0, C1, C2, C3;
    if (MODE == 1) {
        C0 = block_sum_1024(p0); C1 = block_sum_1024(p1);
        C2 = block_sum_1024(p2); C3 = block_sum_1024(p3);
    } else {
        C0 = ws[SCAL + 0]; C1 = ws[SCAL + 1];
        C2 = ws[SCAL + 2]; C3 = ws[SCAL + 3];
    }

    const float mean = S / (float)BB;
    const float denom = T / (float)BB + EPSF;

    float ent = 0.f;
    for (int i = t; i < NN; i += 1024) {
        float a = colLDS[i] / (float)BB;
        float na = a / denom;
        ent = fmaf(na, __logf(na + EPSF), ent);
    }
    float ENT = block_sum_1024(ent);  // = -batch_entropy = bent_loss

    if (t == 0) {
        float var = (SS - (float)BB * mean * mean) / (float)(BB - 1);
        float sd = sqrtf(fmaxf(var, 0.f));
        float sharpe = -mean / (sd + 0.01f);
        sharpe = fminf(fmaxf(sharpe, -10.f), 10.f);
        float conc_loss = -C0 / (float)BB;
        float conf_loss =  C1 / (float)BB;
        float aux = (C3 > 0.f) ? C2 / fmaxf(C3, 1.f) : 0.f;
        out[0] = 1.0f * (-mean)
               + 0.1f * sharpe
               + 0.01f * conc_loss
               + 0.1f * conf_loss
               + 0.01f * ENT
               + 0.1f * aux;
    }
}

extern "C" void kernel_launch(void* const* d_in, const int* in_sizes, int n_in,
                              void* d_out, int out_size, void* d_ws, size_t ws_size,
                              hipStream_t stream) {
    const float* pr = (const float*)d_in[0];
    const float* w  = (const float*)d_in[1];
    const float* cf = (const float*)d_in[2];
    const float* ar = (const float*)d_in[3];
    const float* mk = (const float*)d_in[4];
    const float* sc = (const float*)d_in[5];
    float* ws = (float*)d_ws;
    float* out = (float*)d_out;

    const size_t ldsBytes = 2 * (NN / 4) * sizeof(f32x4);   // 64 KB
    const size_t bfNeed = (size_t)PPF * 4 + (size_t)2048 * NN * 2;  // ~33.6 MB

    if (ws_size >= bfNeed) {
        main_k<1><<<2048, 1024, ldsBytes, stream>>>(pr, w, cf, ar, mk, sc, ws);
        colreduce_k<<<dim3(16, 64), 128, 0, stream>>>(
            (const unsigned short*)(ws + PPF), ws);
        finalize<1><<<1, 1024, 0, stream>>>(pr, ws, out);
    } else {
        init_ws<<<48, 256, 0, stream>>>(ws);
        main_k<0><<<2048, 1024, ldsBytes, stream>>>(pr, w, cf, ar, mk, sc, ws);
        finalize<0><<<1, 1024, 0, stream>>>(pr, ws, out);
    }
}

// Round 13
// 141.605 us; speedup vs baseline: 1.3824x; 1.0284x over previous
//
#include <hip/hip_runtime.h>
#include <math.h>

#define BB 4096
#define NN 8192
#define EPSF 1e-8f

typedef float f32x4 __attribute__((ext_vector_type(4)));
typedef unsigned short u16x4 __attribute__((ext_vector_type(4)));

// ws float layout (MODE 1):
// [0, 8192)      : per-block scalar partials: blk*4 + {conc,conf,rank,nok}
// [8192, 16384)  : final colsum (atomic target, zeroed by main_k block 0)
// [16384, ...)   : bf16 colsum partials [2048][8192] (33.55 MB)
// MODE 0 fallback: SCAL scalars + CS colsum, all atomic.
#define CS   8192
#define PPF  16384
#define SCAL 4096

__device__ __forceinline__ unsigned short f2bf(float f) {
    union { float f; unsigned u; } v; v.f = f;
    unsigned u = v.u + 0x7FFF + ((v.u >> 16) & 1);   // RNE
    return (unsigned short)(u >> 16);
}
__device__ __forceinline__ float bf2f(unsigned short b) {
    union { unsigned u; float f; } v; v.u = (unsigned)b << 16;
    return v.f;
}

__global__ void init_ws(float* __restrict__ ws) {
    int i = blockIdx.x * blockDim.x + threadIdx.x;
    if (i < 12288) ws[SCAL + i] = 0.f;
}

// Fused, bf16-LDS-staged: block (512 thr) owns 2 rows; thread t owns f32x4
// groups {t, t+512, t+1024, t+1536} of each row. Phase 1 NT-streams w once,
// computing f32 rowsums and staging w as bf16 in a 32 KB LDS tile (rowsum is
// exact; only downstream terms see w's 0.2% rounding -> ~1e-5 on output).
// ~33 KB LDS + VGPR<=64 -> 4 blocks/CU = 32 waves = 100% occupancy.
template<int MODE>   // 0: atomic colsum+scalars, 1: bf16 partials
__global__ __launch_bounds__(512) void main_k(
    const float* __restrict__ pr, const float* __restrict__ w,
    const float* __restrict__ cf, const float* __restrict__ ar,
    const float* __restrict__ mk, const float* __restrict__ sc,
    float* ws)
{
    __shared__ u16x4 wbf[2][2048];    // 32 KB: 2 rows x 2048 groups x 4 bf16
    __shared__ float rpark[8][2];     // [wave][row] rowsum partials
    __shared__ float park[2][8][8];   // [row][wave][7 vals]

    const int t = threadIdx.x;
    const int wave = t >> 6, lane = t & 63;
    const int rowBase = blockIdx.x * 2;

    // fold initcol: block 0 zeroes the atomic colsum target (consumed only
    // by colreduce_k, which launches after this kernel completes).
    if (MODE == 1 && blockIdx.x == 0) {
#pragma unroll
        for (int j = 0; j < 16; ++j) ws[CS + j * 512 + t] = 0.f;
    }

    const size_t rbase = (size_t)rowBase * (NN / 4);
    const f32x4* w4 = (const f32x4*)w;
    const f32x4* m4 = (const f32x4*)mk;
    const f32x4* c4 = (const f32x4*)cf;
    const f32x4* a4 = (const f32x4*)ar;
    const f32x4* s4 = (const f32x4*)sc;

    // ---- phase 1: w -> bf16 LDS (8 NT loads), exact f32 rowsums ----
    float rs0, rs1;
    {
        float rsv[2];
#pragma unroll
        for (int rr = 0; rr < 2; ++rr) {
            float acc = 0.f;
#pragma unroll
            for (int j = 0; j < 4; ++j) {
                const int g = j * 512 + t;
                const f32x4 v = __builtin_nontemporal_load(w4 + rbase + rr * 2048 + g);
                acc += (v.x + v.y) + (v.z + v.w);
                u16x4 b;
                b.x = f2bf(v.x); b.y = f2bf(v.y);
                b.z = f2bf(v.z); b.w = f2bf(v.w);
                wbf[rr][g] = b;
            }
            rsv[rr] = acc;
        }
        rs0 = rsv[0]; rs1 = rsv[1];
    }
#pragma unroll
    for (int off = 32; off; off >>= 1) {
        rs0 += __shfl_xor(rs0, off);
        rs1 += __shfl_xor(rs1, off);
    }
    if (lane == 0) { rpark[wave][0] = rs0; rpark[wave][1] = rs1; }
    __syncthreads();   // barrier 1: w tile + rowsum partials visible

    float inv[2];
#pragma unroll
    for (int r = 0; r < 2; ++r) {
        float acc = 0.f;
#pragma unroll
        for (int k = 0; k < 8; ++k) acc += rpark[k][r];
        inv[r] = 1.f / (acc + EPSF);
    }

    float csum[16];
#pragma unroll
    for (int j = 0; j < 16; ++j) csum[j] = 0.f;

    // ---- phase 2: w from LDS (bf16->f32), other 4 arrays NT ----
    // no max-subtraction needed: 20*ar in +-3, sc in +-6 -> exp safe in fp32
#define PROC(WK, MKV, CK, RK, SK, IDX) {                          \
        const float wk = (WK), mval = (MKV);                      \
        conc = fmaf(wk, __logf(wk + EPSF), conc);                 \
        const float wmk = wk * mval;                              \
        tw += wmk; scf = fmaf(wmk, (CK), scf);                    \
        nv += mval;                                               \
        const float er = __expf((RK) * 20.f) * mval;              \
        Zr += er; A = fmaf(er, (SK), A);                          \
        Zs = fmaf(__expf((SK)), mval, Zs);                        \
        csum[IDX] = fmaf(wmk, invr, csum[IDX]); }

#pragma unroll
    for (int rr = 0; rr < 2; ++rr) {
        const size_t base = rbase + (size_t)rr * (NN / 4) + t;
        const float invr = inv[rr];
        float conc = 0.f, scf = 0.f, tw = 0.f, nv = 0.f;
        float Zr = 0.f, A = 0.f, Zs = 0.f;
#pragma unroll
        for (int j = 0; j < 4; ++j) {
            const u16x4 wb = wbf[rr][j * 512 + t];
            f32x4 wv;
            wv.x = bf2f(wb.x); wv.y = bf2f(wb.y);
            wv.z = bf2f(wb.z); wv.w = bf2f(wb.w);
            const f32x4 mv = __builtin_nontemporal_load(m4 + base + j * 512);
            const f32x4 cv = __builtin_nontemporal_load(c4 + base + j * 512);
            const f32x4 rv = __builtin_nontemporal_load(a4 + base + j * 512);
            const f32x4 sv = __builtin_nontemporal_load(s4 + base + j * 512);
            PROC(wv.x, mv.x, cv.x, rv.x, sv.x, j * 4 + 0)
            PROC(wv.y, mv.y, cv.y, rv.y, sv.y, j * 4 + 1)
            PROC(wv.z, mv.z, cv.z, rv.z, sv.z, j * 4 + 2)
            PROC(wv.w, mv.w, cv.w, rv.w, sv.w, j * 4 + 3)
        }
#pragma unroll
        for (int off = 32; off; off >>= 1) {
            conc += __shfl_xor(conc, off);
            scf  += __shfl_xor(scf, off);
            tw   += __shfl_xor(tw, off);
            nv   += __shfl_xor(nv, off);
            Zr   += __shfl_xor(Zr, off);
            A    += __shfl_xor(A, off);
            Zs   += __shfl_xor(Zs, off);
        }
        if (lane == 0) {
            float* p = park[rr][wave];
            p[0] = conc; p[1] = scf; p[2] = tw; p[3] = nv;
            p[4] = Zr;   p[5] = A;   p[6] = Zs;
        }
    }
#undef PROC

    // ---- colsum flush: thread's 16 columns, 2 rows summed ----
    if (MODE == 1) {
        unsigned short* bfrow = (unsigned short*)(ws + PPF) + (size_t)blockIdx.x * NN;
#pragma unroll
        for (int j = 0; j < 4; ++j) {
            u16x4 v;
            v.x = f2bf(csum[j * 4 + 0]); v.y = f2bf(csum[j * 4 + 1]);
            v.z = f2bf(csum[j * 4 + 2]); v.w = f2bf(csum[j * 4 + 3]);
            __builtin_nontemporal_store(v, (u16x4*)bfrow + t + j * 512);
        }
    } else {
#pragma unroll
        for (int j = 0; j < 4; ++j) {
            const int f4 = t + j * 512;
            atomicAdd(&ws[CS + 4 * f4 + 0], csum[j * 4 + 0]);
            atomicAdd(&ws[CS + 4 * f4 + 1], csum[j * 4 + 1]);
            atomicAdd(&ws[CS + 4 * f4 + 2], csum[j * 4 + 2]);
            atomicAdd(&ws[CS + 4 * f4 + 3], csum[j * 4 + 3]);
        }
    }

    __syncthreads();   // barrier 2: park slots visible

    if (t < 64) {      // wave 0: lanes 0..1 finalize the block's 2 rows
        float c0 = 0.f, c1 = 0.f, c2 = 0.f, c3 = 0.f;
        if (lane < 2) {
            float CO = 0, SC = 0, TW = 0, NV = 0, ZR = 0, AA = 0, ZS = 0;
#pragma unroll
            for (int k = 0; k < 8; ++k) {
                const float* p = park[lane][k];
                CO += p[0]; SC += p[1]; TW += p[2]; NV += p[3];
                ZR += p[4]; AA += p[5]; ZS += p[6];
            }
            c0 = CO;
            const float psc = SC / (TW + EPSF);
            const float ct = 1.f / (1.f + __expf(-50.f * pr[rowBase + lane]));
            const float d = psc - ct;
            c1 = d * d;
            if (NV >= 2.f) {
                c2 = (__logf(ZS) - AA / ZR) / NV;   // per-sample ListNet loss
                c3 = 1.f;
            }
        }
        c0 += __shfl_xor(c0, 1);
        c1 += __shfl_xor(c1, 1);
        c2 += __shfl_xor(c2, 1);
        c3 += __shfl_xor(c3, 1);
        if (lane == 0) {
            if (MODE == 1) {
                float* dst = ws + (size_t)blockIdx.x * 4;
                dst[0] = c0; dst[1] = c1; dst[2] = c2; dst[3] = c3;
            } else {
                atomicAdd(&ws[SCAL + 0], c0);
                atomicAdd(&ws[SCAL + 1], c1);
                atomicAdd(&ws[SCAL + 2], c2);
                atomicAdd(&ws[SCAL + 3], c3);
            }
        }
    }
}

// bf16 partial reduce: grid (16,64) x 128 thr; thread sums 32 partial rows
// for its 4 cols, one atomicAdd per col into the final colsum.
__global__ __launch_bounds__(128) void colreduce_k(const unsigned short* __restrict__ src,
                                                   float* __restrict__ ws) {
    const int col4 = blockIdx.x * 128 + threadIdx.x;   // 0..2047 (x4 cols)
    const int k0 = blockIdx.y * 32;
    const u16x4* s4 = (const u16x4*)src;
    float a0 = 0.f, a1 = 0.f, a2 = 0.f, a3 = 0.f;
    for (int k = 0; k < 32; ++k) {
        const u16x4 v = s4[(size_t)(k0 + k) * (NN / 4) + col4];
        a0 += bf2f(v.x); a1 += bf2f(v.y);
        a2 += bf2f(v.z); a3 += bf2f(v.w);
    }
    atomicAdd(&ws[CS + col4 * 4 + 0], a0);
    atomicAdd(&ws[CS + col4 * 4 + 1], a1);
    atomicAdd(&ws[CS + col4 * 4 + 2], a2);
    atomicAdd(&ws[CS + col4 * 4 + 3], a3);
}

__device__ __forceinline__ float block_sum_1024(float v) {
    __shared__ float scm[16];
#pragma unroll
    for (int off = 32; off; off >>= 1) v += __shfl_xor(v, off);
    if ((threadIdx.x & 63) == 0) scm[threadIdx.x >> 6] = v;
    __syncthreads();
    if (threadIdx.x == 0) {
        float a = 0.f;
        for (int k = 0; k < 16; ++k) a += scm[k];
        scm[0] = a;
    }
    __syncthreads();
    float r = scm[0];
    __syncthreads();
    return r;
}

template<int MODE>
__global__ __launch_bounds__(1024) void finalize(
    const float* __restrict__ pr, const float* __restrict__ ws,
    float* __restrict__ out)
{
    __shared__ float colLDS[NN];   // 32 KB
    const int t = threadIdx.x;

    float s = 0.f, ssq = 0.f;
    for (int i = t; i < BB; i += 1024) { float v = pr[i]; s += v; ssq = fmaf(v, v, ssq); }

    float p0 = 0.f, p1 = 0.f, p2 = 0.f, p3 = 0.f;
    if (MODE == 1) {
        for (int b = t; b < 2048; b += 1024) {
            p0 += ws[b * 4 + 0]; p1 += ws[b * 4 + 1];
            p2 += ws[b * 4 + 2]; p3 += ws[b * 4 + 3];
        }
    }

    float Tc = 0.f;
    for (int i = t; i < NN; i += 1024) {
        float cs = ws[CS + i];
        colLDS[i] = cs;
        Tc += cs;
    }

    float S  = block_sum_1024(s);
    float SS = block_sum_1024(ssq);
    float T  = block_sum_1024(Tc);
    float C0, C1, C2, C3;
    if (MODE == 1) {
        C0 = block_sum_1024(p0); C1 = block_sum_1024(p1);
        C2 = block_sum_1024(p2); C3 = block_sum_1024(p3);
    } else {
        C0 = ws[SCAL + 0]; C1 = ws[SCAL + 1];
        C2 = ws[SCAL + 2]; C3 = ws[SCAL + 3];
    }

    const float mean = S / (float)BB;
    const float denom = T / (float)BB + EPSF;

    float ent = 0.f;
    for (int i = t; i < NN; i += 1024) {
        float a = colLDS[i] / (float)BB;
        float na = a / denom;
        ent = fmaf(na, __logf(na + EPSF), ent);
    }
    float ENT = block_sum_1024(ent);  // = -batch_entropy = bent_loss

    if (t == 0) {
        float var = (SS - (float)BB * mean * mean) / (float)(BB - 1);
        float sd = sqrtf(fmaxf(var, 0.f));
        float sharpe = -mean / (sd + 0.01f);
        sharpe = fminf(fmaxf(sharpe, -10.f), 10.f);
        float conc_loss = -C0 / (float)BB;
        float conf_loss =  C1 / (float)BB;
        float aux = (C3 > 0.f) ? C2 / fmaxf(C3, 1.f) : 0.f;
        out[0] = 1.0f * (-mean)
               + 0.1f * sharpe
               + 0.01f * conc_loss
               + 0.1f * conf_loss
               + 0.01f * ENT
               + 0.1f * aux;
    }
}

extern "C" void kernel_launch(void* const* d_in, const int* in_sizes, int n_in,
                              void* d_out, int out_size, void* d_ws, size_t ws_size,
                              hipStream_t stream) {
    const float* pr = (const float*)d_in[0];
    const float* w  = (const float*)d_in[1];
    const float* cf = (const float*)d_in[2];
    const float* ar = (const float*)d_in[3];
    const float* mk = (const float*)d_in[4];
    const float* sc = (const float*)d_in[5];
    float* ws = (float*)d_ws;
    float* out = (float*)d_out;

    const size_t bfNeed = (size_t)PPF * 4 + (size_t)2048 * NN * 2;  // ~33.6 MB

    if (ws_size >= bfNeed) {
        main_k<1><<<2048, 512, 0, stream>>>(pr, w, cf, ar, mk, sc, ws);
        colreduce_k<<<dim3(16, 64), 128, 0, stream>>>(
            (const unsigned short*)(ws + PPF), ws);
        finalize<1><<<1, 1024, 0, stream>>>(pr, ws, out);
    } else {
        init_ws<<<48, 256, 0, stream>>>(ws);
        main_k<0><<<2048, 512, 0, stream>>>(pr, w, cf, ar, mk, sc, ws);
        finalize<0><<<1, 1024, 0, stream>>>(pr, ws, out);
    }
}